// Round 10
// baseline (300.137 us; speedup 1.0000x reference)
//
#include <hip/hip_runtime.h>
#include <math.h>

#define N 1536
#define E 24576
#define HD 128
#define D 1280
#define NW 24    // 1536/64 bitmask words per row
#define RT 16    // rows per block in k_h
#define LDK 40   // padded LDS row length (bf16 elems)

typedef unsigned long long u64;
typedef unsigned short u16;
typedef unsigned int u32;
typedef __attribute__((ext_vector_type(8))) short bf16x8;
typedef __attribute__((ext_vector_type(4))) float f32x4;

__device__ __forceinline__ double lrelu(double v){ return v > 0.0 ? v : 0.2*v; }

// Branch-free f64 exp(x), rel err ~6e-15.
__device__ __forceinline__ double fexp(double x){
    double n = __builtin_rint(x * 1.4426950408889634);
    double r = __builtin_fma(-n, 0.6931471805599453, x);
    r = __builtin_fma(-n, 2.3190468138462996e-17, r);
    double p = 2.505210838544172e-8;
    p = __builtin_fma(p, r, 2.755731922398589e-7);
    p = __builtin_fma(p, r, 2.7557319223985893e-6);
    p = __builtin_fma(p, r, 2.48015873015873e-5);
    p = __builtin_fma(p, r, 1.984126984126984e-4);
    p = __builtin_fma(p, r, 1.3888888888888889e-3);
    p = __builtin_fma(p, r, 8.333333333333333e-3);
    p = __builtin_fma(p, r, 4.1666666666666664e-2);
    p = __builtin_fma(p, r, 1.6666666666666666e-1);
    p = __builtin_fma(p, r, 0.5);
    p = __builtin_fma(p, r, 1.0);
    p = __builtin_fma(p, r, 1.0);
    long long ni = (long long)n;
    double s = __longlong_as_double((u64)(ni + 1023) << 52);
    return (x < -700.0) ? 0.0 : p * s;
}

// Branch-free f32 exp(x), rel err ~2e-7, valid |x| <= 80.
__device__ __forceinline__ float fexpf_(float x){
    float n = __builtin_rintf(x * 1.44269504f);
    float r = __builtin_fmaf(-n, 0.693359375f, x);
    r = __builtin_fmaf(-n, -2.12194440e-4f, r);
    float p = 1.9841270e-4f;
    p = __builtin_fmaf(p, r, 1.3888889e-3f);
    p = __builtin_fmaf(p, r, 8.3333333e-3f);
    p = __builtin_fmaf(p, r, 4.1666667e-2f);
    p = __builtin_fmaf(p, r, 1.6666667e-1f);
    p = __builtin_fmaf(p, r, 0.5f);
    p = __builtin_fmaf(p, r, 1.0f);
    p = __builtin_fmaf(p, r, 1.0f);
    int ni = (int)n;
    float s = __uint_as_float((u32)(ni + 127) << 23);
    return p * s;
}

// f32 -> bf16(hi) + bf16(residual), both RNE
__device__ __forceinline__ void bsplit(float f, u16& h, u16& l){
    unsigned u = __float_as_uint(f);
    unsigned hr = (u + 0x7fffu + ((u>>16)&1u)) >> 16;
    h = (u16)hr;
    float hf = __uint_as_float(hr << 16);
    float r = f - hf;
    unsigned u2 = __float_as_uint(r);
    l = (u16)((u2 + 0x7fffu + ((u2>>16)&1u)) >> 16);
}

// ---- IN bitmask + in-degree incl. self-loop
__global__ void k_deg_in(const int* __restrict__ ei, u64* __restrict__ IN, int* __restrict__ deg){
    int idx = blockIdx.x*blockDim.x + threadIdx.x;
    if (idx < E){
        int s = ei[idx], t = ei[E+idx];
        atomicOr(&IN[(size_t)t*NW + (s>>6)], 1ULL << (s&63));
        atomicAdd(&deg[t], 1);
    } else if (idx < E+N){
        atomicAdd(&deg[idx-E], 1);
    }
}

// ---- exclusive scan of deg -> coff[0..N], cursor copy
__global__ void k_scan(const int* __restrict__ deg, int* __restrict__ coff, int* __restrict__ cursor){
    __shared__ int ls[256];
    int tid = threadIdx.x;
    int v[6]; int s = 0;
    for (int u=0; u<6; u++){ v[u] = s; s += deg[tid*6+u]; }
    ls[tid] = s; __syncthreads();
    for (int d=1; d<256; d<<=1){
        int t2 = (tid>=d) ? ls[tid-d] : 0;
        __syncthreads();
        ls[tid] += t2;
        __syncthreads();
    }
    int base = (tid>0) ? ls[tid-1] : 0;
    for (int u=0; u<6; u++){
        int o = base + v[u];
        coff[tid*6+u] = o; cursor[tid*6+u] = o;
    }
    if (tid==255) coff[N] = ls[255];
}

// ---- fill CSR of in-edge sources
__global__ void k_fill(const int* __restrict__ ei, int* __restrict__ cursor, int* __restrict__ csr_src){
    int idx = blockIdx.x*blockDim.x + threadIdx.x;
    if (idx < E){
        int s = ei[idx], t = ei[E+idx];
        int p = atomicAdd(&cursor[t], 1);
        csr_src[p] = s;
    } else if (idx < E+N){
        int t = idx - E;
        int p = atomicAdd(&cursor[t], 1);
        csr_src[p] = t;
    }
}

// ---- 2-hop reachability v3: 256 threads, 8-chunk-parallel OR-union phase.
__global__ void k_mrow(const u64* __restrict__ IN, u64* __restrict__ Mb,
                       u16* __restrict__ cols, int* __restrict__ cnt){
    int i = blockIdx.x, tid = threadIdx.x;   // blockDim = 256
    __shared__ u64 m1[NW];
    __shared__ int scn[64];
    __shared__ u16 lst[N];
    __shared__ u64 Racc[8][32];
    u64 b = 0;
    if (tid < NW){
        b = IN[(size_t)i*NW + tid];
        if ((i>>6) == tid) b |= 1ULL << (i&63);
        m1[tid] = b;
    }
    int pc = (tid < NW) ? __popcll(b) : 0;
    if (tid < 64) scn[tid] = pc;
    __syncthreads();
    for (int d=1; d<64; d<<=1){
        int v = (tid>=d && tid<64) ? scn[tid-d] : 0;
        __syncthreads();
        if (tid < 64) scn[tid] += v;
        __syncthreads();
    }
    if (tid < 64){
        int idx = scn[tid] - pc;
        u64 bb = b;
        while (bb){
            int k = __ffsll((unsigned long long)bb) - 1;
            bb &= bb - 1;
            lst[idx++] = (u16)(tid*64 + k);
        }
    }
    __syncthreads();
    int nn = scn[63];
    int w = tid & 31, ch = tid >> 5;         // 8 chunks x 32 word-slots (24 used)
    u64 R = 0;
    if (w < NW){
        for (int u=ch; u<nn; u+=8) R |= IN[(size_t)lst[u]*NW + w];
    }
    Racc[ch][w] = R;
    __syncthreads();
    u64 R2 = 0;
    if (tid < NW){
        R2 = m1[tid];
        #pragma unroll
        for (int c2=0; c2<8; c2++) R2 |= Racc[c2][tid];
        Mb[(size_t)i*NW + tid] = R2;
    }
    int pc2 = (tid < NW) ? __popcll(R2) : 0;
    if (tid < 64) scn[tid] = pc2;
    __syncthreads();
    for (int d=1; d<64; d<<=1){
        int v = (tid>=d && tid<64) ? scn[tid-d] : 0;
        __syncthreads();
        if (tid < 64) scn[tid] += v;
        __syncthreads();
    }
    if (tid == 63) cnt[i] = scn[63];
    if (tid < 64){
        int idx = scn[tid] - pc2;
        u64 bb = R2;
        while (bb){
            int k = __ffsll((unsigned long long)bb) - 1;
            bb &= bb - 1;
            cols[(size_t)i*N + idx++] = (u16)(tid*64 + k);
        }
    }
}

// ---- h = x @ W1, all-f32. grid (D/256, N/RT).
__global__ void k_h(const float* __restrict__ x, const float* __restrict__ W1, float* __restrict__ h32){
    int rb = blockIdx.y*RT, tid = threadIdx.x;
    int col = blockIdx.x*256 + tid;
    __shared__ float xL[RT*HD];   // 8 KB
    for (int u=tid; u<RT*HD; u+=256) xL[u] = x[(size_t)rb*HD + u];
    __syncthreads();
    float acc[RT];
    #pragma unroll
    for (int r=0; r<RT; r++) acc[r] = 0.0f;
    const float* wp = &W1[col];
    #pragma unroll 4
    for (int k=0; k<HD; k++){
        float w = wp[(size_t)k*D];
        #pragma unroll
        for (int r=0; r<RT; r++) acc[r] = __builtin_fmaf(w, xL[r*HD + k], acc[r]);
    }
    #pragma unroll
    for (int r=0; r<RT; r++) h32[(size_t)(rb+r)*D + col] = acc[r];
}

// ---- va = W1 @ a_src1, vb = W1 @ a_dst1 (f64). One block, 256 threads.
__global__ void k_wa(const float* __restrict__ W1, const float* __restrict__ as1,
                     const float* __restrict__ ad1, double* __restrict__ vab){
    __shared__ double red[256];
    int tid = threadIdx.x;
    int k = tid >> 1, half = tid & 1;
    const float* wr = &W1[(size_t)k*D + half*640];
    const float* ar = &as1[half*640];
    const float* br = &ad1[half*640];
    double a = 0, bs = 0;
    for (int d=0; d<640; d++){
        double wv = (double)wr[d];
        a  += wv * (double)ar[d];
        bs += wv * (double)br[d];
    }
    red[tid] = a; __syncthreads();
    if (half == 0) vab[k] = red[tid] + red[tid+1];
    __syncthreads();
    red[tid] = bs; __syncthreads();
    if (half == 0) vab[128+k] = red[tid] + red[tid+1];
}

// ---- hs1[i] = x[i]·va, hd1[i] = x[i]·vb. grid N/256.
__global__ void k_hs(const float* __restrict__ x, const double* __restrict__ vab,
                     double* __restrict__ hs1, double* __restrict__ hd1){
    __shared__ double vaL[HD], vbL[HD];
    int tid = threadIdx.x;
    if (tid < HD) vaL[tid] = vab[tid];
    else          vbL[tid-HD] = vab[tid];
    __syncthreads();
    int i = blockIdx.x*256 + tid;
    const float* xr = &x[(size_t)i*HD];
    double a = 0, bs = 0;
    #pragma unroll 4
    for (int d=0; d<HD; d++){
        double xv = (double)xr[d];
        a  += xv * vaL[d];
        bs += xv * vbL[d];
    }
    hs1[i] = a; hd1[i] = bs;
}

// ---- split xo into bf16 hi/lo planes
__global__ void k_split_x(const float* __restrict__ xo, u16* __restrict__ Xhi, u16* __restrict__ Xlo){
    int idx = (blockIdx.x*256 + threadIdx.x)*4;
    float4 v = *(const float4*)&xo[idx];
    ushort4 h, l;
    bsplit(v.x, h.x, l.x); bsplit(v.y, h.y, l.y);
    bsplit(v.z, h.z, l.z); bsplit(v.w, h.w, l.w);
    *(ushort4*)&Xhi[idx] = h;
    *(ushort4*)&Xlo[idx] = l;
}

// ---- stage-1 GAT: single-pass softmax, f32 gather, bf16 hi/lo epilogue
__global__ void k_gat(const int* __restrict__ coff, const int* __restrict__ csr_src,
                      const double* __restrict__ hs1, const double* __restrict__ hd1,
                      const float* __restrict__ h32,
                      const float* __restrict__ b1, const float* __restrict__ w2,
                      u16* __restrict__ Ghi, u16* __restrict__ Glo){
    int t = blockIdx.x, tid = threadIdx.x;
    int o0 = coff[t], o1 = coff[t+1], dg = o1 - o0;
    __shared__ double red[256];
    __shared__ float als[256];
    __shared__ int ssrc[256];
    __shared__ double DD;
    double hdt = hd1[t];
    double dsum = 0.0;
    for (int j=tid; j<dg; j+=256){
        int s = csr_src[o0+j];
        double e = lrelu(hs1[s] + hdt);
        dsum += fexp(e);
    }
    red[tid] = dsum; __syncthreads();
    for (int step=128; step>0; step>>=1){
        if (tid < step) red[tid] += red[tid+step];
        __syncthreads();
    }
    if (tid == 0) DD = red[0];
    __syncthreads();
    double Dv = DD;
    float acc[5] = {0,0,0,0,0};
    for (int base=0; base<dg; base+=256){
        int j = base + tid;
        if (j < dg){
            int s = csr_src[o0+j];
            double e = lrelu(hs1[s] + hdt);
            als[tid] = (float)(fexp(e)/Dv); ssrc[tid] = s;
        }
        __syncthreads();
        int lim = min(256, dg-base);
        for (int u=0; u<lim; u+=2){
            float a0 = als[u];
            int s0 = ssrc[u];
            bool h1 = (u+1 < lim);
            float a1 = h1 ? als[u+1] : 0.0f;
            int s1 = h1 ? ssrc[u+1] : s0;
            const float* hp0 = &h32[(size_t)s0*D];
            const float* hp1 = &h32[(size_t)s1*D];
            #pragma unroll
            for (int q=0; q<5; q++)
                acc[q] = __builtin_fmaf(a1, hp1[tid + 256*q],
                         __builtin_fmaf(a0, hp0[tid + 256*q], acc[q]));
        }
        __syncthreads();
    }
    #pragma unroll
    for (int q=0; q<5; q++){
        int d = tid + 256*q;
        float g = (acc[q] + b1[d]) * w2[d];
        u16 gh, gl;
        bsplit(g, gh, gl);
        Ghi[(size_t)t*D + d] = gh;
        Glo[(size_t)t*D + d] = gl;
    }
}

// ---- dense H2 = G @ Xo^T via split-bf16 MFMA (hi*hi + lo*hi + hi*lo).
__global__ __launch_bounds__(256)
void k_h2mm(const u16* __restrict__ Ghi, const u16* __restrict__ Glo,
            const u16* __restrict__ Xhi, const u16* __restrict__ Xlo,
            float* __restrict__ H2){
    __shared__ u16 As_hi[128*LDK], As_lo[128*LDK], Bs_hi[128*LDK], Bs_lo[128*LDK]; // 40 KB
    int tid = threadIdx.x;
    int bm = blockIdx.x / 12, bn = blockIdx.x % 12;
    int r0 = tid >> 2;
    int kc = (tid & 3) * 8;
    size_t baseA = (size_t)(bm*128 + r0)*D + kc;
    size_t baseB = (size_t)(bn*128 + r0)*D + kc;
    int w = tid >> 6, L = tid & 63;
    int l16 = L & 15, qd = L >> 4;
    int wm = (w & 1)*64, wn = (w >> 1)*64;
    f32x4 acc[4][4];
    #pragma unroll
    for (int a=0; a<4; a++)
        #pragma unroll
        for (int b=0; b<4; b++) acc[a][b] = (f32x4){0.f,0.f,0.f,0.f};

    for (int kb = 0; kb < D; kb += 32){
        uint4 ah0 = *(const uint4*)&Ghi[baseA + kb];
        uint4 ah1 = *(const uint4*)&Ghi[baseA + (size_t)64*D + kb];
        uint4 al0 = *(const uint4*)&Glo[baseA + kb];
        uint4 al1 = *(const uint4*)&Glo[baseA + (size_t)64*D + kb];
        uint4 bh0 = *(const uint4*)&Xhi[baseB + kb];
        uint4 bh1 = *(const uint4*)&Xhi[baseB + (size_t)64*D + kb];
        uint4 bl0 = *(const uint4*)&Xlo[baseB + kb];
        uint4 bl1 = *(const uint4*)&Xlo[baseB + (size_t)64*D + kb];
        __syncthreads();
        *(uint4*)&As_hi[r0*LDK + kc] = ah0;
        *(uint4*)&As_hi[(r0+64)*LDK + kc] = ah1;
        *(uint4*)&As_lo[r0*LDK + kc] = al0;
        *(uint4*)&As_lo[(r0+64)*LDK + kc] = al1;
        *(uint4*)&Bs_hi[r0*LDK + kc] = bh0;
        *(uint4*)&Bs_hi[(r0+64)*LDK + kc] = bh1;
        *(uint4*)&Bs_lo[r0*LDK + kc] = bl0;
        *(uint4*)&Bs_lo[(r0+64)*LDK + kc] = bl1;
        __syncthreads();
        bf16x8 ahi[4], alo[4];
        #pragma unroll
        for (int tm=0; tm<4; tm++){
            ahi[tm] = *(const bf16x8*)&As_hi[(wm + tm*16 + l16)*LDK + qd*8];
            alo[tm] = *(const bf16x8*)&As_lo[(wm + tm*16 + l16)*LDK + qd*8];
        }
        #pragma unroll
        for (int tn=0; tn<4; tn++){
            bf16x8 bh = *(const bf16x8*)&Bs_hi[(wn + tn*16 + l16)*LDK + qd*8];
            bf16x8 bl = *(const bf16x8*)&Bs_lo[(wn + tn*16 + l16)*LDK + qd*8];
            #pragma unroll
            for (int tm=0; tm<4; tm++){
                acc[tm][tn] = __builtin_amdgcn_mfma_f32_16x16x32_bf16(ahi[tm], bh, acc[tm][tn], 0, 0, 0);
                acc[tm][tn] = __builtin_amdgcn_mfma_f32_16x16x32_bf16(alo[tm], bh, acc[tm][tn], 0, 0, 0);
                acc[tm][tn] = __builtin_amdgcn_mfma_f32_16x16x32_bf16(ahi[tm], bl, acc[tm][tn], 0, 0, 0);
            }
        }
    }
    #pragma unroll
    for (int tm=0; tm<4; tm++){
        int rbase = bm*128 + wm + tm*16 + qd*4;
        #pragma unroll
        for (int tn=0; tn<4; tn++){
            int cg = bn*128 + wn + tn*16 + l16;
            #pragma unroll
            for (int reg=0; reg<4; reg++)
                H2[(size_t)(rbase+reg)*N + cg] = acc[tm][tn][reg];
        }
    }
}

// ---- fused stage-2 score + rank v4: LDS-staged output rows, coalesced writes.
__global__ void k_score_rank(const float* __restrict__ H2, const u64* __restrict__ Mb,
                             const u16* __restrict__ cols, const int* __restrict__ cnt,
                             const int* __restrict__ coff, const int* __restrict__ csr_src,
                             const float* __restrict__ pas2, const float* __restrict__ pad2,
                             const float* __restrict__ pb2, float* __restrict__ out){
    int i = blockIdx.x, tid = threadIdx.x;
    __shared__ float HL[N];              // 6 KB
    __shared__ u64 MbL[NW];
    __shared__ u16 clL[N];               // 3 KB
    __shared__ u64 KL[N];                // 12 KB
    __shared__ float sigS[N];            // 6 KB
    __shared__ unsigned char keepB[N];   // 1.5 KB
    float* keepO = out + (size_t)N*N;
    for (int c=tid; c<N; c+=256){ sigS[c] = 0.0f; keepB[c] = 0; }
    for (int d=tid; d<N; d+=256) HL[d] = H2[(size_t)i*N + d];
    if (tid < NW) MbL[tid] = Mb[(size_t)i*NW + tid];
    __syncthreads();
    float as2 = pas2[0], ad2 = pad2[0];
    double b2 = (double)pb2[0];
    int c0 = cnt[i];
    for (int c=tid; c<c0; c+=256){
        int t = cols[(size_t)i*N + c];
        float ht = HL[t];
        float zd = ad2 * ht;
        int o0 = coff[t], o1 = coff[t+1];
        double den = 0.0, nu = 0.0;
        for (int p=o0; p<o1; p++){
            int s = csr_src[p];
            bool v = (MbL[s>>6] >> (s&63)) & 1ULL;
            float hs = HL[s];
            float z = __builtin_fmaf(as2, hs, zd);
            float e = z > 0.0f ? z : 0.2f*z;
            e = fminf(fmaxf(e, -80.0f), 80.0f);
            float w = v ? fexpf_(e) : 0.0f;
            den += (double)w;
            nu  += (double)(w * hs);
        }
        float sf = (float)(nu / fmax(den, 1e-12) + b2);
        clL[c] = (u16)t;
        u32 kb = __float_as_uint(sf);
        kb = (kb & 0x80000000u) ? ~kb : (kb | 0x80000000u);   // order-preserving map
        KL[c] = ((u64)kb << 16) | (u32)(1535 - t);            // tie-break: smaller col wins
    }
    __syncthreads();
    int k = (c0 + 1) >> 1;                 // ceil(0.5*size)
    for (int p=tid; p<c0; p+=256){
        u64 Kp = KL[p];
        int r = 0;
        for (int q=0; q<c0; q++) r += (int)(KL[q] > Kp);
        if (r < k){
            u32 kb = (u32)(Kp >> 16);
            u32 orig = (kb & 0x80000000u) ? (kb & 0x7fffffffu) : ~kb;
            float sf = __uint_as_float(orig);
            int col = clL[p];
            sigS[col] = 1.0f/(1.0f + fexpf_(fminf(fmaxf(-sf,-80.f),80.f)));
            keepB[col] = 1;
        }
    }
    __syncthreads();
    for (int c=tid; c<N; c+=256){
        out[(size_t)i*N + c]   = sigS[c];
        keepO[(size_t)i*N + c] = keepB[c] ? 1.0f : 0.0f;
    }
}

extern "C" void kernel_launch(void* const* d_in, const int* in_sizes, int n_in,
                              void* d_out, int out_size, void* d_ws, size_t ws_size,
                              hipStream_t stream){
    const float* x   = (const float*)d_in[0];
    const float* xo  = (const float*)d_in[1];
    const int*   ei  = (const int*)  d_in[2];
    // d_in[3] = batch (unused)
    const float* W1  = (const float*)d_in[4];
    const float* as1 = (const float*)d_in[5];
    const float* ad1 = (const float*)d_in[6];
    const float* b1  = (const float*)d_in[7];
    const float* w2  = (const float*)d_in[8];
    const float* as2 = (const float*)d_in[9];
    const float* ad2 = (const float*)d_in[10];
    const float* b2  = (const float*)d_in[11];
    float* out = (float*)d_out;

    char* w = (char*)d_ws;
    size_t o = 0;
    auto alloc = [&](size_t b)->char*{ char* r = w + o; o = (o + b + 255) & ~(size_t)255; return r; };

    float*  h32   = (float*) alloc((size_t)N*D*4);
    float*  H2    = (float*) alloc((size_t)N*N*4);
    u16*    Ghi   = (u16*)   alloc((size_t)N*D*2);
    u16*    Glo   = (u16*)   alloc((size_t)N*D*2);
    u16*    Xhi   = (u16*)   alloc((size_t)N*D*2);
    u16*    Xlo   = (u16*)   alloc((size_t)N*D*2);
    u64*    IN    = (u64*)   alloc((size_t)N*NW*8);   // 294912 B (256-aligned)
    int*    deg   = (int*)   alloc((size_t)N*4);      // contiguous after IN -> one memset
    u64*    Mb    = (u64*)   alloc((size_t)N*NW*8);
    double* hs1   = (double*)alloc((size_t)N*8);
    double* hd1   = (double*)alloc((size_t)N*8);
    double* vab   = (double*)alloc((size_t)256*8);
    int*    coff  = (int*)   alloc((size_t)(N+1)*4);
    int*    cursor= (int*)   alloc((size_t)N*4);
    int*    csr   = (int*)   alloc((size_t)(E+N)*4);
    u16*    cols  = (u16*)   alloc((size_t)N*N*2);
    int*    cnt   = (int*)   alloc((size_t)N*4);

    hipMemsetAsync(IN, 0, (size_t)N*NW*8 + (size_t)N*4, stream);  // IN + deg

    k_deg_in <<<(E+N+255)/256, 256, 0, stream>>>(ei, IN, deg);
    k_scan   <<<1, 256, 0, stream>>>(deg, coff, cursor);
    k_fill   <<<(E+N+255)/256, 256, 0, stream>>>(ei, cursor, csr);
    k_split_x<<<(N*D)/(256*4), 256, 0, stream>>>(xo, Xhi, Xlo);
    k_mrow   <<<N, 256, 0, stream>>>(IN, Mb, cols, cnt);
    k_h      <<<dim3(D/256, N/RT), 256, 0, stream>>>(x, W1, h32);
    k_wa     <<<1, 256, 0, stream>>>(W1, as1, ad1, vab);
    k_hs     <<<N/256, 256, 0, stream>>>(x, vab, hs1, hd1);
    k_gat    <<<N, 256, 0, stream>>>(coff, csr, hs1, hd1, h32, b1, w2, Ghi, Glo);
    k_h2mm   <<<144, 256, 0, stream>>>(Ghi, Glo, Xhi, Xlo, H2);
    k_score_rank<<<N, 256, 0, stream>>>(H2, Mb, cols, cnt, coff, csr, as2, ad2, b2, out);
}

// Round 11
// 239.087 us; speedup vs baseline: 1.2553x; 1.2553x over previous
//
#include <hip/hip_runtime.h>
#include <math.h>

#define N 1536
#define E 24576
#define HD 128
#define D 1280
#define NW 24    // 1536/64 bitmask words per row
#define RT 16    // rows per block in k_h
#define LDK 40   // padded LDS row length (bf16 elems)

typedef unsigned long long u64;
typedef unsigned short u16;
typedef unsigned int u32;
typedef __attribute__((ext_vector_type(8))) short bf16x8;
typedef __attribute__((ext_vector_type(4))) float f32x4;

__device__ __forceinline__ double lrelu(double v){ return v > 0.0 ? v : 0.2*v; }

// Branch-free f64 exp(x), rel err ~6e-15.
__device__ __forceinline__ double fexp(double x){
    double n = __builtin_rint(x * 1.4426950408889634);
    double r = __builtin_fma(-n, 0.6931471805599453, x);
    r = __builtin_fma(-n, 2.3190468138462996e-17, r);
    double p = 2.505210838544172e-8;
    p = __builtin_fma(p, r, 2.755731922398589e-7);
    p = __builtin_fma(p, r, 2.7557319223985893e-6);
    p = __builtin_fma(p, r, 2.48015873015873e-5);
    p = __builtin_fma(p, r, 1.984126984126984e-4);
    p = __builtin_fma(p, r, 1.3888888888888889e-3);
    p = __builtin_fma(p, r, 8.333333333333333e-3);
    p = __builtin_fma(p, r, 4.1666666666666664e-2);
    p = __builtin_fma(p, r, 1.6666666666666666e-1);
    p = __builtin_fma(p, r, 0.5);
    p = __builtin_fma(p, r, 1.0);
    p = __builtin_fma(p, r, 1.0);
    long long ni = (long long)n;
    double s = __longlong_as_double((u64)(ni + 1023) << 52);
    return (x < -700.0) ? 0.0 : p * s;
}

// Branch-free f32 exp(x), rel err ~2e-7, valid |x| <= 80.
__device__ __forceinline__ float fexpf_(float x){
    float n = __builtin_rintf(x * 1.44269504f);
    float r = __builtin_fmaf(-n, 0.693359375f, x);
    r = __builtin_fmaf(-n, -2.12194440e-4f, r);
    float p = 1.9841270e-4f;
    p = __builtin_fmaf(p, r, 1.3888889e-3f);
    p = __builtin_fmaf(p, r, 8.3333333e-3f);
    p = __builtin_fmaf(p, r, 4.1666667e-2f);
    p = __builtin_fmaf(p, r, 1.6666667e-1f);
    p = __builtin_fmaf(p, r, 0.5f);
    p = __builtin_fmaf(p, r, 1.0f);
    p = __builtin_fmaf(p, r, 1.0f);
    int ni = (int)n;
    float s = __uint_as_float((u32)(ni + 127) << 23);
    return p * s;
}

// f32 -> bf16(hi) + bf16(residual), both RNE
__device__ __forceinline__ void bsplit(float f, u16& h, u16& l){
    unsigned u = __float_as_uint(f);
    unsigned hr = (u + 0x7fffu + ((u>>16)&1u)) >> 16;
    h = (u16)hr;
    float hf = __uint_as_float(hr << 16);
    float r = f - hf;
    unsigned u2 = __float_as_uint(r);
    l = (u16)((u2 + 0x7fffu + ((u2>>16)&1u)) >> 16);
}

// ---- IN bitmask + in-degree incl. self-loop
__global__ void k_deg_in(const int* __restrict__ ei, u64* __restrict__ IN, int* __restrict__ deg){
    int idx = blockIdx.x*blockDim.x + threadIdx.x;
    if (idx < E){
        int s = ei[idx], t = ei[E+idx];
        atomicOr(&IN[(size_t)t*NW + (s>>6)], 1ULL << (s&63));
        atomicAdd(&deg[t], 1);
    } else if (idx < E+N){
        atomicAdd(&deg[idx-E], 1);
    }
}

// ---- exclusive scan of deg -> coff[0..N], cursor copy
__global__ void k_scan(const int* __restrict__ deg, int* __restrict__ coff, int* __restrict__ cursor){
    __shared__ int ls[256];
    int tid = threadIdx.x;
    int v[6]; int s = 0;
    for (int u=0; u<6; u++){ v[u] = s; s += deg[tid*6+u]; }
    ls[tid] = s; __syncthreads();
    for (int d=1; d<256; d<<=1){
        int t2 = (tid>=d) ? ls[tid-d] : 0;
        __syncthreads();
        ls[tid] += t2;
        __syncthreads();
    }
    int base = (tid>0) ? ls[tid-1] : 0;
    for (int u=0; u<6; u++){
        int o = base + v[u];
        coff[tid*6+u] = o; cursor[tid*6+u] = o;
    }
    if (tid==255) coff[N] = ls[255];
}

// ---- fill CSR of in-edge sources
__global__ void k_fill(const int* __restrict__ ei, int* __restrict__ cursor, int* __restrict__ csr_src){
    int idx = blockIdx.x*blockDim.x + threadIdx.x;
    if (idx < E){
        int s = ei[idx], t = ei[E+idx];
        int p = atomicAdd(&cursor[t], 1);
        csr_src[p] = s;
    } else if (idx < E+N){
        int t = idx - E;
        int p = atomicAdd(&cursor[t], 1);
        csr_src[p] = t;
    }
}

// ---- 2-hop reachability (R9-proven v2): 64 threads, 1-hop list in LDS, 4 OR chains.
__global__ void k_mrow(const u64* __restrict__ IN, u64* __restrict__ Mb,
                       u16* __restrict__ cols, int* __restrict__ cnt){
    int i = blockIdx.x, ln = threadIdx.x;   // blockDim = 64
    __shared__ u64 m1[NW];
    __shared__ int scn[64];
    __shared__ u16 lst[N];
    u64 b = 0;
    if (ln < NW){
        b = IN[(size_t)i*NW + ln];
        if ((i>>6) == ln) b |= 1ULL << (i&63);
        m1[ln] = b;
    }
    int pc = (ln < NW) ? __popcll(b) : 0;
    scn[ln] = pc; __syncthreads();
    for (int d=1; d<64; d<<=1){
        int v = (ln>=d) ? scn[ln-d] : 0;
        __syncthreads();
        scn[ln] += v;
        __syncthreads();
    }
    {
        int idx = scn[ln] - pc;
        u64 bb = b;
        while (bb){
            int k = __ffsll((unsigned long long)bb) - 1;
            bb &= bb - 1;
            lst[idx++] = (u16)(ln*64 + k);
        }
    }
    __syncthreads();
    int nn = scn[63];
    u64 R0 = b, R1 = 0, R2 = 0, R3 = 0;
    int u = 0;
    if (ln < NW){
        for (; u+3 < nn; u += 4){
            R0 |= IN[(size_t)lst[u  ]*NW + ln];
            R1 |= IN[(size_t)lst[u+1]*NW + ln];
            R2 |= IN[(size_t)lst[u+2]*NW + ln];
            R3 |= IN[(size_t)lst[u+3]*NW + ln];
        }
        for (; u < nn; u++) R0 |= IN[(size_t)lst[u]*NW + ln];
    }
    u64 R = (R0 | R1) | (R2 | R3);
    if (ln < NW) Mb[(size_t)i*NW + ln] = R;
    __syncthreads();
    pc = (ln < NW) ? __popcll(R) : 0;
    scn[ln] = pc; __syncthreads();
    for (int d=1; d<64; d<<=1){
        int v = (ln>=d) ? scn[ln-d] : 0;
        __syncthreads();
        scn[ln] += v;
        __syncthreads();
    }
    if (ln == 63) cnt[i] = scn[63];
    int idx = scn[ln] - pc;
    u64 bb = R;
    while (bb){
        int k = __ffsll((unsigned long long)bb) - 1;
        bb &= bb - 1;
        cols[(size_t)i*N + idx++] = (u16)(ln*64 + k);
    }
}

// ---- h = x @ W1, all-f32. grid (D/256, N/RT).
__global__ void k_h(const float* __restrict__ x, const float* __restrict__ W1, float* __restrict__ h32){
    int rb = blockIdx.y*RT, tid = threadIdx.x;
    int col = blockIdx.x*256 + tid;
    __shared__ float xL[RT*HD];   // 8 KB
    for (int u=tid; u<RT*HD; u+=256) xL[u] = x[(size_t)rb*HD + u];
    __syncthreads();
    float acc[RT];
    #pragma unroll
    for (int r=0; r<RT; r++) acc[r] = 0.0f;
    const float* wp = &W1[col];
    #pragma unroll 4
    for (int k=0; k<HD; k++){
        float w = wp[(size_t)k*D];
        #pragma unroll
        for (int r=0; r<RT; r++) acc[r] = __builtin_fmaf(w, xL[r*HD + k], acc[r]);
    }
    #pragma unroll
    for (int r=0; r<RT; r++) h32[(size_t)(rb+r)*D + col] = acc[r];
}

// ---- hs1 = h@a_src1, hd1 = h@a_dst1 (R9-proven, f64 accum over f32 h)
__global__ void k_hv(const float* __restrict__ h32, const float* __restrict__ as1,
                     const float* __restrict__ ad1, double* __restrict__ hs1, double* __restrict__ hd1){
    int i = blockIdx.x, tid = threadIdx.x;
    __shared__ double ra[256], rb[256];
    double a = 0, b = 0;
    for (int d=tid; d<D; d+=256){
        double hv = (double)h32[(size_t)i*D + d];
        a += hv * (double)as1[d];
        b += hv * (double)ad1[d];
    }
    ra[tid] = a; rb[tid] = b; __syncthreads();
    for (int s=128; s>0; s>>=1){
        if (tid < s){ ra[tid] += ra[tid+s]; rb[tid] += rb[tid+s]; }
        __syncthreads();
    }
    if (tid == 0){ hs1[i] = ra[0]; hd1[i] = rb[0]; }
}

// ---- split xo into bf16 hi/lo planes
__global__ void k_split_x(const float* __restrict__ xo, u16* __restrict__ Xhi, u16* __restrict__ Xlo){
    int idx = (blockIdx.x*256 + threadIdx.x)*4;
    float4 v = *(const float4*)&xo[idx];
    ushort4 h, l;
    bsplit(v.x, h.x, l.x); bsplit(v.y, h.y, l.y);
    bsplit(v.z, h.z, l.z); bsplit(v.w, h.w, l.w);
    *(ushort4*)&Xhi[idx] = h;
    *(ushort4*)&Xlo[idx] = l;
}

// ---- stage-1 GAT: single-pass softmax, f32 gather, bf16 hi/lo epilogue
__global__ void k_gat(const int* __restrict__ coff, const int* __restrict__ csr_src,
                      const double* __restrict__ hs1, const double* __restrict__ hd1,
                      const float* __restrict__ h32,
                      const float* __restrict__ b1, const float* __restrict__ w2,
                      u16* __restrict__ Ghi, u16* __restrict__ Glo){
    int t = blockIdx.x, tid = threadIdx.x;
    int o0 = coff[t], o1 = coff[t+1], dg = o1 - o0;
    __shared__ double red[256];
    __shared__ float als[256];
    __shared__ int ssrc[256];
    __shared__ double DD;
    double hdt = hd1[t];
    double dsum = 0.0;
    for (int j=tid; j<dg; j+=256){
        int s = csr_src[o0+j];
        double e = lrelu(hs1[s] + hdt);
        dsum += fexp(e);
    }
    red[tid] = dsum; __syncthreads();
    for (int step=128; step>0; step>>=1){
        if (tid < step) red[tid] += red[tid+step];
        __syncthreads();
    }
    if (tid == 0) DD = red[0];
    __syncthreads();
    double Dv = DD;
    float acc[5] = {0,0,0,0,0};
    for (int base=0; base<dg; base+=256){
        int j = base + tid;
        if (j < dg){
            int s = csr_src[o0+j];
            double e = lrelu(hs1[s] + hdt);
            als[tid] = (float)(fexp(e)/Dv); ssrc[tid] = s;
        }
        __syncthreads();
        int lim = min(256, dg-base);
        for (int u=0; u<lim; u+=2){
            float a0 = als[u];
            int s0 = ssrc[u];
            bool h1 = (u+1 < lim);
            float a1 = h1 ? als[u+1] : 0.0f;
            int s1 = h1 ? ssrc[u+1] : s0;
            const float* hp0 = &h32[(size_t)s0*D];
            const float* hp1 = &h32[(size_t)s1*D];
            #pragma unroll
            for (int q=0; q<5; q++)
                acc[q] = __builtin_fmaf(a1, hp1[tid + 256*q],
                         __builtin_fmaf(a0, hp0[tid + 256*q], acc[q]));
        }
        __syncthreads();
    }
    #pragma unroll
    for (int q=0; q<5; q++){
        int d = tid + 256*q;
        float g = (acc[q] + b1[d]) * w2[d];
        u16 gh, gl;
        bsplit(g, gh, gl);
        Ghi[(size_t)t*D + d] = gh;
        Glo[(size_t)t*D + d] = gl;
    }
}

// ---- dense H2 = G @ Xo^T via split-bf16 MFMA (hi*hi + lo*hi + hi*lo).
__global__ __launch_bounds__(256)
void k_h2mm(const u16* __restrict__ Ghi, const u16* __restrict__ Glo,
            const u16* __restrict__ Xhi, const u16* __restrict__ Xlo,
            float* __restrict__ H2){
    __shared__ u16 As_hi[128*LDK], As_lo[128*LDK], Bs_hi[128*LDK], Bs_lo[128*LDK]; // 40 KB
    int tid = threadIdx.x;
    int bm = blockIdx.x / 12, bn = blockIdx.x % 12;
    int r0 = tid >> 2;
    int kc = (tid & 3) * 8;
    size_t baseA = (size_t)(bm*128 + r0)*D + kc;
    size_t baseB = (size_t)(bn*128 + r0)*D + kc;
    int w = tid >> 6, L = tid & 63;
    int l16 = L & 15, qd = L >> 4;
    int wm = (w & 1)*64, wn = (w >> 1)*64;
    f32x4 acc[4][4];
    #pragma unroll
    for (int a=0; a<4; a++)
        #pragma unroll
        for (int b=0; b<4; b++) acc[a][b] = (f32x4){0.f,0.f,0.f,0.f};

    for (int kb = 0; kb < D; kb += 32){
        uint4 ah0 = *(const uint4*)&Ghi[baseA + kb];
        uint4 ah1 = *(const uint4*)&Ghi[baseA + (size_t)64*D + kb];
        uint4 al0 = *(const uint4*)&Glo[baseA + kb];
        uint4 al1 = *(const uint4*)&Glo[baseA + (size_t)64*D + kb];
        uint4 bh0 = *(const uint4*)&Xhi[baseB + kb];
        uint4 bh1 = *(const uint4*)&Xhi[baseB + (size_t)64*D + kb];
        uint4 bl0 = *(const uint4*)&Xlo[baseB + kb];
        uint4 bl1 = *(const uint4*)&Xlo[baseB + (size_t)64*D + kb];
        __syncthreads();
        *(uint4*)&As_hi[r0*LDK + kc] = ah0;
        *(uint4*)&As_hi[(r0+64)*LDK + kc] = ah1;
        *(uint4*)&As_lo[r0*LDK + kc] = al0;
        *(uint4*)&As_lo[(r0+64)*LDK + kc] = al1;
        *(uint4*)&Bs_hi[r0*LDK + kc] = bh0;
        *(uint4*)&Bs_hi[(r0+64)*LDK + kc] = bh1;
        *(uint4*)&Bs_lo[r0*LDK + kc] = bl0;
        *(uint4*)&Bs_lo[(r0+64)*LDK + kc] = bl1;
        __syncthreads();
        bf16x8 ahi[4], alo[4];
        #pragma unroll
        for (int tm=0; tm<4; tm++){
            ahi[tm] = *(const bf16x8*)&As_hi[(wm + tm*16 + l16)*LDK + qd*8];
            alo[tm] = *(const bf16x8*)&As_lo[(wm + tm*16 + l16)*LDK + qd*8];
        }
        #pragma unroll
        for (int tn=0; tn<4; tn++){
            bf16x8 bh = *(const bf16x8*)&Bs_hi[(wn + tn*16 + l16)*LDK + qd*8];
            bf16x8 bl = *(const bf16x8*)&Bs_lo[(wn + tn*16 + l16)*LDK + qd*8];
            #pragma unroll
            for (int tm=0; tm<4; tm++){
                acc[tm][tn] = __builtin_amdgcn_mfma_f32_16x16x32_bf16(ahi[tm], bh, acc[tm][tn], 0, 0, 0);
                acc[tm][tn] = __builtin_amdgcn_mfma_f32_16x16x32_bf16(alo[tm], bh, acc[tm][tn], 0, 0, 0);
                acc[tm][tn] = __builtin_amdgcn_mfma_f32_16x16x32_bf16(ahi[tm], bl, acc[tm][tn], 0, 0, 0);
            }
        }
    }
    #pragma unroll
    for (int tm=0; tm<4; tm++){
        int rbase = bm*128 + wm + tm*16 + qd*4;
        #pragma unroll
        for (int tn=0; tn<4; tn++){
            int cg = bn*128 + wn + tn*16 + l16;
            #pragma unroll
            for (int reg=0; reg<4; reg++)
                H2[(size_t)(rbase+reg)*N + cg] = acc[tm][tn][reg];
        }
    }
}

// ---- fused stage-2 score + rank v5: LDS-staged outputs + 4-way unrolled edge walk.
__global__ void k_score_rank(const float* __restrict__ H2, const u64* __restrict__ Mb,
                             const u16* __restrict__ cols, const int* __restrict__ cnt,
                             const int* __restrict__ coff, const int* __restrict__ csr_src,
                             const float* __restrict__ pas2, const float* __restrict__ pad2,
                             const float* __restrict__ pb2, float* __restrict__ out){
    int i = blockIdx.x, tid = threadIdx.x;
    __shared__ float HL[N];              // 6 KB
    __shared__ u64 MbL[NW];
    __shared__ u16 clL[N];               // 3 KB
    __shared__ u64 KL[N];                // 12 KB
    __shared__ float sigS[N];            // 6 KB
    __shared__ unsigned char keepB[N];   // 1.5 KB
    float* keepO = out + (size_t)N*N;
    for (int c=tid; c<N; c+=256){ sigS[c] = 0.0f; keepB[c] = 0; }
    for (int d=tid; d<N; d+=256) HL[d] = H2[(size_t)i*N + d];
    if (tid < NW) MbL[tid] = Mb[(size_t)i*NW + tid];
    __syncthreads();
    float as2 = pas2[0], ad2 = pad2[0];
    double b2 = (double)pb2[0];
    int c0 = cnt[i];
    for (int c=tid; c<c0; c+=256){
        int t = cols[(size_t)i*N + c];
        float ht = HL[t];
        float zd = ad2 * ht;
        int o0 = coff[t], o1 = coff[t+1];
        double den = 0.0, nu = 0.0;
        int p = o0;
        for (; p+3 < o1; p += 4){
            int s0 = csr_src[p], s1 = csr_src[p+1], s2 = csr_src[p+2], s3 = csr_src[p+3];
            float h0 = HL[s0], h1 = HL[s1], h2 = HL[s2], h3 = HL[s3];
            bool v0 = (MbL[s0>>6] >> (s0&63)) & 1ULL;
            bool v1 = (MbL[s1>>6] >> (s1&63)) & 1ULL;
            bool v2 = (MbL[s2>>6] >> (s2&63)) & 1ULL;
            bool v3 = (MbL[s3>>6] >> (s3&63)) & 1ULL;
            float z0 = __builtin_fmaf(as2, h0, zd), z1 = __builtin_fmaf(as2, h1, zd);
            float z2 = __builtin_fmaf(as2, h2, zd), z3 = __builtin_fmaf(as2, h3, zd);
            float e0 = z0 > 0.f ? z0 : 0.2f*z0;  e0 = fminf(fmaxf(e0,-80.f),80.f);
            float e1 = z1 > 0.f ? z1 : 0.2f*z1;  e1 = fminf(fmaxf(e1,-80.f),80.f);
            float e2 = z2 > 0.f ? z2 : 0.2f*z2;  e2 = fminf(fmaxf(e2,-80.f),80.f);
            float e3 = z3 > 0.f ? z3 : 0.2f*z3;  e3 = fminf(fmaxf(e3,-80.f),80.f);
            float w0 = v0 ? fexpf_(e0) : 0.0f;
            float w1 = v1 ? fexpf_(e1) : 0.0f;
            float w2v = v2 ? fexpf_(e2) : 0.0f;
            float w3 = v3 ? fexpf_(e3) : 0.0f;
            den += (double)w0 + (double)w1 + (double)w2v + (double)w3;
            nu  += (double)(w0*h0) + (double)(w1*h1) + (double)(w2v*h2) + (double)(w3*h3);
        }
        for (; p < o1; p++){
            int s = csr_src[p];
            bool v = (MbL[s>>6] >> (s&63)) & 1ULL;
            float hs = HL[s];
            float z = __builtin_fmaf(as2, hs, zd);
            float e = z > 0.0f ? z : 0.2f*z;
            e = fminf(fmaxf(e, -80.0f), 80.0f);
            float w = v ? fexpf_(e) : 0.0f;
            den += (double)w;
            nu  += (double)(w * hs);
        }
        float sf = (float)(nu / fmax(den, 1e-12) + b2);
        clL[c] = (u16)t;
        u32 kb = __float_as_uint(sf);
        kb = (kb & 0x80000000u) ? ~kb : (kb | 0x80000000u);   // order-preserving map
        KL[c] = ((u64)kb << 16) | (u32)(1535 - t);            // tie-break: smaller col wins
    }
    __syncthreads();
    int k = (c0 + 1) >> 1;                 // ceil(0.5*size)
    for (int p=tid; p<c0; p+=256){
        u64 Kp = KL[p];
        int r = 0;
        for (int q=0; q<c0; q++) r += (int)(KL[q] > Kp);
        if (r < k){
            u32 kb = (u32)(Kp >> 16);
            u32 orig = (kb & 0x80000000u) ? (kb & 0x7fffffffu) : ~kb;
            float sf = __uint_as_float(orig);
            int col = clL[p];
            sigS[col] = 1.0f/(1.0f + fexpf_(fminf(fmaxf(-sf,-80.f),80.f)));
            keepB[col] = 1;
        }
    }
    __syncthreads();
    for (int c=tid; c<N; c+=256){
        out[(size_t)i*N + c]   = sigS[c];
        keepO[(size_t)i*N + c] = keepB[c] ? 1.0f : 0.0f;
    }
}

extern "C" void kernel_launch(void* const* d_in, const int* in_sizes, int n_in,
                              void* d_out, int out_size, void* d_ws, size_t ws_size,
                              hipStream_t stream){
    const float* x   = (const float*)d_in[0];
    const float* xo  = (const float*)d_in[1];
    const int*   ei  = (const int*)  d_in[2];
    // d_in[3] = batch (unused)
    const float* W1  = (const float*)d_in[4];
    const float* as1 = (const float*)d_in[5];
    const float* ad1 = (const float*)d_in[6];
    const float* b1  = (const float*)d_in[7];
    const float* w2  = (const float*)d_in[8];
    const float* as2 = (const float*)d_in[9];
    const float* ad2 = (const float*)d_in[10];
    const float* b2  = (const float*)d_in[11];
    float* out = (float*)d_out;

    char* w = (char*)d_ws;
    size_t o = 0;
    auto alloc = [&](size_t b)->char*{ char* r = w + o; o = (o + b + 255) & ~(size_t)255; return r; };

    float*  h32   = (float*) alloc((size_t)N*D*4);
    float*  H2    = (float*) alloc((size_t)N*N*4);
    u16*    Ghi   = (u16*)   alloc((size_t)N*D*2);
    u16*    Glo   = (u16*)   alloc((size_t)N*D*2);
    u16*    Xhi   = (u16*)   alloc((size_t)N*D*2);
    u16*    Xlo   = (u16*)   alloc((size_t)N*D*2);
    u64*    IN    = (u64*)   alloc((size_t)N*NW*8);   // 294912 B, 256-aligned
    int*    deg   = (int*)   alloc((size_t)N*4);      // contiguous after IN -> one memset
    u64*    Mb    = (u64*)   alloc((size_t)N*NW*8);
    double* hs1   = (double*)alloc((size_t)N*8);
    double* hd1   = (double*)alloc((size_t)N*8);
    int*    coff  = (int*)   alloc((size_t)(N+1)*4);
    int*    cursor= (int*)   alloc((size_t)N*4);
    int*    csr   = (int*)   alloc((size_t)(E+N)*4);
    u16*    cols  = (u16*)   alloc((size_t)N*N*2);
    int*    cnt   = (int*)   alloc((size_t)N*4);

    hipMemsetAsync(IN, 0, (size_t)N*NW*8 + (size_t)N*4, stream);  // IN + deg

    k_deg_in <<<(E+N+255)/256, 256, 0, stream>>>(ei, IN, deg);
    k_scan   <<<1, 256, 0, stream>>>(deg, coff, cursor);
    k_fill   <<<(E+N+255)/256, 256, 0, stream>>>(ei, cursor, csr);
    k_split_x<<<(N*D)/(256*4), 256, 0, stream>>>(xo, Xhi, Xlo);
    k_mrow   <<<N, 64, 0, stream>>>(IN, Mb, cols, cnt);
    k_h      <<<dim3(D/256, N/RT), 256, 0, stream>>>(x, W1, h32);
    k_hv     <<<N, 256, 0, stream>>>(h32, as1, ad1, hs1, hd1);
    k_gat    <<<N, 256, 0, stream>>>(coff, csr, hs1, hd1, h32, b1, w2, Ghi, Glo);
    k_h2mm   <<<144, 256, 0, stream>>>(Ghi, Glo, Xhi, Xlo, H2);
    k_score_rank<<<N, 256, 0, stream>>>(H2, Mb, cols, cnt, coff, csr, as2, ad2, b2, out);
}

// Round 12
// 227.201 us; speedup vs baseline: 1.3210x; 1.0523x over previous
//
#include <hip/hip_runtime.h>
#include <math.h>

#define N 1536
#define E 24576
#define HD 128
#define D 1280
#define NW 24    // 1536/64 bitmask words per row
#define RT 16    // rows per block in k_h
#define LDK 40   // padded LDS row length (bf16 elems)

typedef unsigned long long u64;
typedef unsigned short u16;
typedef unsigned int u32;
typedef __attribute__((ext_vector_type(8))) short bf16x8;
typedef __attribute__((ext_vector_type(4))) float f32x4;

__device__ __forceinline__ double lrelu(double v){ return v > 0.0 ? v : 0.2*v; }

// Branch-free f64 exp(x), rel err ~6e-15.
__device__ __forceinline__ double fexp(double x){
    double n = __builtin_rint(x * 1.4426950408889634);
    double r = __builtin_fma(-n, 0.6931471805599453, x);
    r = __builtin_fma(-n, 2.3190468138462996e-17, r);
    double p = 2.505210838544172e-8;
    p = __builtin_fma(p, r, 2.755731922398589e-7);
    p = __builtin_fma(p, r, 2.7557319223985893e-6);
    p = __builtin_fma(p, r, 2.48015873015873e-5);
    p = __builtin_fma(p, r, 1.984126984126984e-4);
    p = __builtin_fma(p, r, 1.3888888888888889e-3);
    p = __builtin_fma(p, r, 8.333333333333333e-3);
    p = __builtin_fma(p, r, 4.1666666666666664e-2);
    p = __builtin_fma(p, r, 1.6666666666666666e-1);
    p = __builtin_fma(p, r, 0.5);
    p = __builtin_fma(p, r, 1.0);
    p = __builtin_fma(p, r, 1.0);
    long long ni = (long long)n;
    double s = __longlong_as_double((u64)(ni + 1023) << 52);
    return (x < -700.0) ? 0.0 : p * s;
}

// Branch-free f32 exp(x), rel err ~2e-7, valid |x| <= 80.
__device__ __forceinline__ float fexpf_(float x){
    float n = __builtin_rintf(x * 1.44269504f);
    float r = __builtin_fmaf(-n, 0.693359375f, x);
    r = __builtin_fmaf(-n, -2.12194440e-4f, r);
    float p = 1.9841270e-4f;
    p = __builtin_fmaf(p, r, 1.3888889e-3f);
    p = __builtin_fmaf(p, r, 8.3333333e-3f);
    p = __builtin_fmaf(p, r, 4.1666667e-2f);
    p = __builtin_fmaf(p, r, 1.6666667e-1f);
    p = __builtin_fmaf(p, r, 0.5f);
    p = __builtin_fmaf(p, r, 1.0f);
    p = __builtin_fmaf(p, r, 1.0f);
    int ni = (int)n;
    float s = __uint_as_float((u32)(ni + 127) << 23);
    return p * s;
}

// f32 -> bf16(hi) + bf16(residual), both RNE
__device__ __forceinline__ void bsplit(float f, u16& h, u16& l){
    unsigned u = __float_as_uint(f);
    unsigned hr = (u + 0x7fffu + ((u>>16)&1u)) >> 16;
    h = (u16)hr;
    float hf = __uint_as_float(hr << 16);
    float r = f - hf;
    unsigned u2 = __float_as_uint(r);
    l = (u16)((u2 + 0x7fffu + ((u2>>16)&1u)) >> 16);
}

// ---- IN bitmask + in-degree incl. self-loop
__global__ void k_deg_in(const int* __restrict__ ei, u64* __restrict__ IN, int* __restrict__ deg){
    int idx = blockIdx.x*blockDim.x + threadIdx.x;
    if (idx < E){
        int s = ei[idx], t = ei[E+idx];
        atomicOr(&IN[(size_t)t*NW + (s>>6)], 1ULL << (s&63));
        atomicAdd(&deg[t], 1);
    } else if (idx < E+N){
        atomicAdd(&deg[idx-E], 1);
    }
}

// ---- exclusive scan of deg -> coff[0..N], cursor copy
__global__ void k_scan(const int* __restrict__ deg, int* __restrict__ coff, int* __restrict__ cursor){
    __shared__ int ls[256];
    int tid = threadIdx.x;
    int v[6]; int s = 0;
    for (int u=0; u<6; u++){ v[u] = s; s += deg[tid*6+u]; }
    ls[tid] = s; __syncthreads();
    for (int d=1; d<256; d<<=1){
        int t2 = (tid>=d) ? ls[tid-d] : 0;
        __syncthreads();
        ls[tid] += t2;
        __syncthreads();
    }
    int base = (tid>0) ? ls[tid-1] : 0;
    for (int u=0; u<6; u++){
        int o = base + v[u];
        coff[tid*6+u] = o; cursor[tid*6+u] = o;
    }
    if (tid==255) coff[N] = ls[255];
}

// ---- fill CSR of in-edge sources
__global__ void k_fill(const int* __restrict__ ei, int* __restrict__ cursor, int* __restrict__ csr_src){
    int idx = blockIdx.x*blockDim.x + threadIdx.x;
    if (idx < E){
        int s = ei[idx], t = ei[E+idx];
        int p = atomicAdd(&cursor[t], 1);
        csr_src[p] = s;
    } else if (idx < E+N){
        int t = idx - E;
        int p = atomicAdd(&cursor[t], 1);
        csr_src[p] = t;
    }
}

// ---- 2-hop reachability (R9-proven): 64 threads, 1-hop list in LDS, 4 OR chains.
__global__ void k_mrow(const u64* __restrict__ IN, u64* __restrict__ Mb,
                       u16* __restrict__ cols, int* __restrict__ cnt){
    int i = blockIdx.x, ln = threadIdx.x;   // blockDim = 64
    __shared__ u64 m1[NW];
    __shared__ int scn[64];
    __shared__ u16 lst[N];
    u64 b = 0;
    if (ln < NW){
        b = IN[(size_t)i*NW + ln];
        if ((i>>6) == ln) b |= 1ULL << (i&63);
        m1[ln] = b;
    }
    int pc = (ln < NW) ? __popcll(b) : 0;
    scn[ln] = pc; __syncthreads();
    for (int d=1; d<64; d<<=1){
        int v = (ln>=d) ? scn[ln-d] : 0;
        __syncthreads();
        scn[ln] += v;
        __syncthreads();
    }
    {
        int idx = scn[ln] - pc;
        u64 bb = b;
        while (bb){
            int k = __ffsll((unsigned long long)bb) - 1;
            bb &= bb - 1;
            lst[idx++] = (u16)(ln*64 + k);
        }
    }
    __syncthreads();
    int nn = scn[63];
    u64 R0 = b, R1 = 0, R2 = 0, R3 = 0;
    int u = 0;
    if (ln < NW){
        for (; u+3 < nn; u += 4){
            R0 |= IN[(size_t)lst[u  ]*NW + ln];
            R1 |= IN[(size_t)lst[u+1]*NW + ln];
            R2 |= IN[(size_t)lst[u+2]*NW + ln];
            R3 |= IN[(size_t)lst[u+3]*NW + ln];
        }
        for (; u < nn; u++) R0 |= IN[(size_t)lst[u]*NW + ln];
    }
    u64 R = (R0 | R1) | (R2 | R3);
    if (ln < NW) Mb[(size_t)i*NW + ln] = R;
    __syncthreads();
    pc = (ln < NW) ? __popcll(R) : 0;
    scn[ln] = pc; __syncthreads();
    for (int d=1; d<64; d<<=1){
        int v = (ln>=d) ? scn[ln-d] : 0;
        __syncthreads();
        scn[ln] += v;
        __syncthreads();
    }
    if (ln == 63) cnt[i] = scn[63];
    int idx = scn[ln] - pc;
    u64 bb = R;
    while (bb){
        int k = __ffsll((unsigned long long)bb) - 1;
        bb &= bb - 1;
        cols[(size_t)i*N + idx++] = (u16)(ln*64 + k);
    }
}

// ---- h = x @ W1, all-f32. grid (D/256, N/RT).
__global__ void k_h(const float* __restrict__ x, const float* __restrict__ W1, float* __restrict__ h32){
    int rb = blockIdx.y*RT, tid = threadIdx.x;
    int col = blockIdx.x*256 + tid;
    __shared__ float xL[RT*HD];   // 8 KB
    for (int u=tid; u<RT*HD; u+=256) xL[u] = x[(size_t)rb*HD + u];
    __syncthreads();
    float acc[RT];
    #pragma unroll
    for (int r=0; r<RT; r++) acc[r] = 0.0f;
    const float* wp = &W1[col];
    #pragma unroll 4
    for (int k=0; k<HD; k++){
        float w = wp[(size_t)k*D];
        #pragma unroll
        for (int r=0; r<RT; r++) acc[r] = __builtin_fmaf(w, xL[r*HD + k], acc[r]);
    }
    #pragma unroll
    for (int r=0; r<RT; r++) h32[(size_t)(rb+r)*D + col] = acc[r];
}

// ---- hs1 = h@a_src1, hd1 = h@a_dst1 (f64 accum over f32 h)
__global__ void k_hv(const float* __restrict__ h32, const float* __restrict__ as1,
                     const float* __restrict__ ad1, double* __restrict__ hs1, double* __restrict__ hd1){
    int i = blockIdx.x, tid = threadIdx.x;
    __shared__ double ra[256], rb[256];
    double a = 0, b = 0;
    for (int d=tid; d<D; d+=256){
        double hv = (double)h32[(size_t)i*D + d];
        a += hv * (double)as1[d];
        b += hv * (double)ad1[d];
    }
    ra[tid] = a; rb[tid] = b; __syncthreads();
    for (int s=128; s>0; s>>=1){
        if (tid < s){ ra[tid] += ra[tid+s]; rb[tid] += rb[tid+s]; }
        __syncthreads();
    }
    if (tid == 0){ hs1[i] = ra[0]; hd1[i] = rb[0]; }
}

// ---- split xo into bf16 hi/lo planes
__global__ void k_split_x(const float* __restrict__ xo, u16* __restrict__ Xhi, u16* __restrict__ Xlo){
    int idx = (blockIdx.x*256 + threadIdx.x)*4;
    float4 v = *(const float4*)&xo[idx];
    ushort4 h, l;
    bsplit(v.x, h.x, l.x); bsplit(v.y, h.y, l.y);
    bsplit(v.z, h.z, l.z); bsplit(v.w, h.w, l.w);
    *(ushort4*)&Xhi[idx] = h;
    *(ushort4*)&Xlo[idx] = l;
}

// ---- stage-1 GAT: single-pass softmax, f32 gather, bf16 hi/lo epilogue
__global__ void k_gat(const int* __restrict__ coff, const int* __restrict__ csr_src,
                      const double* __restrict__ hs1, const double* __restrict__ hd1,
                      const float* __restrict__ h32,
                      const float* __restrict__ b1, const float* __restrict__ w2,
                      u16* __restrict__ Ghi, u16* __restrict__ Glo){
    int t = blockIdx.x, tid = threadIdx.x;
    int o0 = coff[t], o1 = coff[t+1], dg = o1 - o0;
    __shared__ double red[256];
    __shared__ float als[256];
    __shared__ int ssrc[256];
    __shared__ double DD;
    double hdt = hd1[t];
    double dsum = 0.0;
    for (int j=tid; j<dg; j+=256){
        int s = csr_src[o0+j];
        double e = lrelu(hs1[s] + hdt);
        dsum += fexp(e);
    }
    red[tid] = dsum; __syncthreads();
    for (int step=128; step>0; step>>=1){
        if (tid < step) red[tid] += red[tid+step];
        __syncthreads();
    }
    if (tid == 0) DD = red[0];
    __syncthreads();
    double Dv = DD;
    float acc[5] = {0,0,0,0,0};
    for (int base=0; base<dg; base+=256){
        int j = base + tid;
        if (j < dg){
            int s = csr_src[o0+j];
            double e = lrelu(hs1[s] + hdt);
            als[tid] = (float)(fexp(e)/Dv); ssrc[tid] = s;
        }
        __syncthreads();
        int lim = min(256, dg-base);
        for (int u=0; u<lim; u+=2){
            float a0 = als[u];
            int s0 = ssrc[u];
            bool h1 = (u+1 < lim);
            float a1 = h1 ? als[u+1] : 0.0f;
            int s1 = h1 ? ssrc[u+1] : s0;
            const float* hp0 = &h32[(size_t)s0*D];
            const float* hp1 = &h32[(size_t)s1*D];
            #pragma unroll
            for (int q=0; q<5; q++)
                acc[q] = __builtin_fmaf(a1, hp1[tid + 256*q],
                         __builtin_fmaf(a0, hp0[tid + 256*q], acc[q]));
        }
        __syncthreads();
    }
    #pragma unroll
    for (int q=0; q<5; q++){
        int d = tid + 256*q;
        float g = (acc[q] + b1[d]) * w2[d];
        u16 gh, gl;
        bsplit(g, gh, gl);
        Ghi[(size_t)t*D + d] = gh;
        Glo[(size_t)t*D + d] = gl;
    }
}

// ---- dense H2 = G @ Xo^T via split-bf16 MFMA, v2:
// split-K x2 (288 blocks -> 2 blocks/CU), 512 threads / 8 waves per block
// (wave tile 64x32), partials in Hp[2] summed by k_score_rank.
__global__ __launch_bounds__(512, 4)
void k_h2mm(const u16* __restrict__ Ghi, const u16* __restrict__ Glo,
            const u16* __restrict__ Xhi, const u16* __restrict__ Xlo,
            float* __restrict__ Hp){
    __shared__ u16 As_hi[128*LDK], As_lo[128*LDK], Bs_hi[128*LDK], Bs_lo[128*LDK]; // 40 KB
    int tid = threadIdx.x;
    int ks = blockIdx.x & 1;
    int tile = blockIdx.x >> 1;
    int bm = tile / 12, bn = tile % 12;
    int r0 = tid >> 2;            // 0..127
    int kc = (tid & 3) * 8;       // 0,8,16,24
    int k0 = ks * 640;
    size_t baseA = (size_t)(bm*128 + r0)*D + k0 + kc;
    size_t baseB = (size_t)(bn*128 + r0)*D + k0 + kc;
    int w = tid >> 6, L = tid & 63;
    int l16 = L & 15, qd = L >> 4;
    int wm = (w & 1)*64, wn = (w >> 1)*32;
    f32x4 acc[4][2];
    #pragma unroll
    for (int a=0; a<4; a++)
        #pragma unroll
        for (int b=0; b<2; b++) acc[a][b] = (f32x4){0.f,0.f,0.f,0.f};

    for (int kb = 0; kb < 640; kb += 32){
        uint4 ah = *(const uint4*)&Ghi[baseA + kb];
        uint4 al = *(const uint4*)&Glo[baseA + kb];
        uint4 bh = *(const uint4*)&Xhi[baseB + kb];
        uint4 bl = *(const uint4*)&Xlo[baseB + kb];
        __syncthreads();   // previous compute done
        *(uint4*)&As_hi[r0*LDK + kc] = ah;
        *(uint4*)&As_lo[r0*LDK + kc] = al;
        *(uint4*)&Bs_hi[r0*LDK + kc] = bh;
        *(uint4*)&Bs_lo[r0*LDK + kc] = bl;
        __syncthreads();   // tiles ready
        bf16x8 ahi[4], alo[4];
        #pragma unroll
        for (int tm=0; tm<4; tm++){
            ahi[tm] = *(const bf16x8*)&As_hi[(wm + tm*16 + l16)*LDK + qd*8];
            alo[tm] = *(const bf16x8*)&As_lo[(wm + tm*16 + l16)*LDK + qd*8];
        }
        #pragma unroll
        for (int tn=0; tn<2; tn++){
            bf16x8 bhf = *(const bf16x8*)&Bs_hi[(wn + tn*16 + l16)*LDK + qd*8];
            bf16x8 blf = *(const bf16x8*)&Bs_lo[(wn + tn*16 + l16)*LDK + qd*8];
            #pragma unroll
            for (int tm=0; tm<4; tm++){
                acc[tm][tn] = __builtin_amdgcn_mfma_f32_16x16x32_bf16(ahi[tm], bhf, acc[tm][tn], 0, 0, 0);
                acc[tm][tn] = __builtin_amdgcn_mfma_f32_16x16x32_bf16(alo[tm], bhf, acc[tm][tn], 0, 0, 0);
                acc[tm][tn] = __builtin_amdgcn_mfma_f32_16x16x32_bf16(ahi[tm], blf, acc[tm][tn], 0, 0, 0);
            }
        }
    }
    // epilogue: C/D layout col=lane&15, row=quad*4+reg
    float* HO = Hp + (size_t)ks*N*N;
    #pragma unroll
    for (int tm=0; tm<4; tm++){
        int rbase = bm*128 + wm + tm*16 + qd*4;
        #pragma unroll
        for (int tn=0; tn<2; tn++){
            int cg = bn*128 + wn + tn*16 + l16;
            #pragma unroll
            for (int reg=0; reg<4; reg++)
                HO[(size_t)(rbase+reg)*N + cg] = acc[tm][tn][reg];
        }
    }
}

// ---- fused stage-2 score + rank: LDS-staged outputs, 4-way unrolled edge walk.
// HL row = sum of the two split-K partials.
__global__ void k_score_rank(const float* __restrict__ Hp, const u64* __restrict__ Mb,
                             const u16* __restrict__ cols, const int* __restrict__ cnt,
                             const int* __restrict__ coff, const int* __restrict__ csr_src,
                             const float* __restrict__ pas2, const float* __restrict__ pad2,
                             const float* __restrict__ pb2, float* __restrict__ out){
    int i = blockIdx.x, tid = threadIdx.x;
    __shared__ float HL[N];              // 6 KB
    __shared__ u64 MbL[NW];
    __shared__ u16 clL[N];               // 3 KB
    __shared__ u64 KL[N];                // 12 KB
    __shared__ float sigS[N];            // 6 KB
    __shared__ unsigned char keepB[N];   // 1.5 KB
    float* keepO = out + (size_t)N*N;
    for (int c=tid; c<N; c+=256){ sigS[c] = 0.0f; keepB[c] = 0; }
    for (int d=tid; d<N; d+=256)
        HL[d] = Hp[(size_t)i*N + d] + Hp[(size_t)N*N + (size_t)i*N + d];
    if (tid < NW) MbL[tid] = Mb[(size_t)i*NW + tid];
    __syncthreads();
    float as2 = pas2[0], ad2 = pad2[0];
    double b2 = (double)pb2[0];
    int c0 = cnt[i];
    for (int c=tid; c<c0; c+=256){
        int t = cols[(size_t)i*N + c];
        float ht = HL[t];
        float zd = ad2 * ht;
        int o0 = coff[t], o1 = coff[t+1];
        double den = 0.0, nu = 0.0;
        int p = o0;
        for (; p+3 < o1; p += 4){
            int s0 = csr_src[p], s1 = csr_src[p+1], s2 = csr_src[p+2], s3 = csr_src[p+3];
            float h0 = HL[s0], h1 = HL[s1], h2 = HL[s2], h3 = HL[s3];
            bool v0 = (MbL[s0>>6] >> (s0&63)) & 1ULL;
            bool v1 = (MbL[s1>>6] >> (s1&63)) & 1ULL;
            bool v2 = (MbL[s2>>6] >> (s2&63)) & 1ULL;
            bool v3 = (MbL[s3>>6] >> (s3&63)) & 1ULL;
            float z0 = __builtin_fmaf(as2, h0, zd), z1 = __builtin_fmaf(as2, h1, zd);
            float z2 = __builtin_fmaf(as2, h2, zd), z3 = __builtin_fmaf(as2, h3, zd);
            float e0 = z0 > 0.f ? z0 : 0.2f*z0;  e0 = fminf(fmaxf(e0,-80.f),80.f);
            float e1 = z1 > 0.f ? z1 : 0.2f*z1;  e1 = fminf(fmaxf(e1,-80.f),80.f);
            float e2 = z2 > 0.f ? z2 : 0.2f*z2;  e2 = fminf(fmaxf(e2,-80.f),80.f);
            float e3 = z3 > 0.f ? z3 : 0.2f*z3;  e3 = fminf(fmaxf(e3,-80.f),80.f);
            float w0 = v0 ? fexpf_(e0) : 0.0f;
            float w1 = v1 ? fexpf_(e1) : 0.0f;
            float w2v = v2 ? fexpf_(e2) : 0.0f;
            float w3 = v3 ? fexpf_(e3) : 0.0f;
            den += (double)w0 + (double)w1 + (double)w2v + (double)w3;
            nu  += (double)(w0*h0) + (double)(w1*h1) + (double)(w2v*h2) + (double)(w3*h3);
        }
        for (; p < o1; p++){
            int s = csr_src[p];
            bool v = (MbL[s>>6] >> (s&63)) & 1ULL;
            float hs = HL[s];
            float z = __builtin_fmaf(as2, hs, zd);
            float e = z > 0.0f ? z : 0.2f*z;
            e = fminf(fmaxf(e, -80.0f), 80.0f);
            float w = v ? fexpf_(e) : 0.0f;
            den += (double)w;
            nu  += (double)(w * hs);
        }
        float sf = (float)(nu / fmax(den, 1e-12) + b2);
        clL[c] = (u16)t;
        u32 kb = __float_as_uint(sf);
        kb = (kb & 0x80000000u) ? ~kb : (kb | 0x80000000u);   // order-preserving map
        KL[c] = ((u64)kb << 16) | (u32)(1535 - t);            // tie-break: smaller col wins
    }
    __syncthreads();
    int k = (c0 + 1) >> 1;                 // ceil(0.5*size)
    for (int p=tid; p<c0; p+=256){
        u64 Kp = KL[p];
        int r = 0;
        for (int q=0; q<c0; q++) r += (int)(KL[q] > Kp);
        if (r < k){
            u32 kb = (u32)(Kp >> 16);
            u32 orig = (kb & 0x80000000u) ? (kb & 0x7fffffffu) : ~kb;
            float sf = __uint_as_float(orig);
            int col = clL[p];
            sigS[col] = 1.0f/(1.0f + fexpf_(fminf(fmaxf(-sf,-80.f),80.f)));
            keepB[col] = 1;
        }
    }
    __syncthreads();
    for (int c=tid; c<N; c+=256){
        out[(size_t)i*N + c]   = sigS[c];
        keepO[(size_t)i*N + c] = keepB[c] ? 1.0f : 0.0f;
    }
}

extern "C" void kernel_launch(void* const* d_in, const int* in_sizes, int n_in,
                              void* d_out, int out_size, void* d_ws, size_t ws_size,
                              hipStream_t stream){
    const float* x   = (const float*)d_in[0];
    const float* xo  = (const float*)d_in[1];
    const int*   ei  = (const int*)  d_in[2];
    // d_in[3] = batch (unused)
    const float* W1  = (const float*)d_in[4];
    const float* as1 = (const float*)d_in[5];
    const float* ad1 = (const float*)d_in[6];
    const float* b1  = (const float*)d_in[7];
    const float* w2  = (const float*)d_in[8];
    const float* as2 = (const float*)d_in[9];
    const float* ad2 = (const float*)d_in[10];
    const float* b2  = (const float*)d_in[11];
    float* out = (float*)d_out;

    char* w = (char*)d_ws;
    size_t o = 0;
    auto alloc = [&](size_t b)->char*{ char* r = w + o; o = (o + b + 255) & ~(size_t)255; return r; };

    float*  h32   = (float*) alloc((size_t)N*D*4);
    float*  Hp    = (float*) alloc((size_t)2*N*N*4);   // 2 split-K partials
    u16*    Ghi   = (u16*)   alloc((size_t)N*D*2);
    u16*    Glo   = (u16*)   alloc((size_t)N*D*2);
    u16*    Xhi   = (u16*)   alloc((size_t)N*D*2);
    u16*    Xlo   = (u16*)   alloc((size_t)N*D*2);
    u64*    IN    = (u64*)   alloc((size_t)N*NW*8);   // 294912 B, 256-aligned
    int*    deg   = (int*)   alloc((size_t)N*4);      // contiguous after IN -> one memset
    u64*    Mb    = (u64*)   alloc((size_t)N*NW*8);
    double* hs1   = (double*)alloc((size_t)N*8);
    double* hd1   = (double*)alloc((size_t)N*8);
    int*    coff  = (int*)   alloc((size_t)(N+1)*4);
    int*    cursor= (int*)   alloc((size_t)N*4);
    int*    csr   = (int*)   alloc((size_t)(E+N)*4);
    u16*    cols  = (u16*)   alloc((size_t)N*N*2);
    int*    cnt   = (int*)   alloc((size_t)N*4);

    hipMemsetAsync(IN, 0, (size_t)N*NW*8 + (size_t)N*4, stream);  // IN + deg

    k_deg_in <<<(E+N+255)/256, 256, 0, stream>>>(ei, IN, deg);
    k_scan   <<<1, 256, 0, stream>>>(deg, coff, cursor);
    k_fill   <<<(E+N+255)/256, 256, 0, stream>>>(ei, cursor, csr);
    k_split_x<<<(N*D)/(256*4), 256, 0, stream>>>(xo, Xhi, Xlo);
    k_mrow   <<<N, 64, 0, stream>>>(IN, Mb, cols, cnt);
    k_h      <<<dim3(D/256, N/RT), 256, 0, stream>>>(x, W1, h32);
    k_hv     <<<N, 256, 0, stream>>>(h32, as1, ad1, hs1, hd1);
    k_gat    <<<N, 256, 0, stream>>>(coff, csr, hs1, hd1, h32, b1, w2, Ghi, Glo);
    k_h2mm   <<<288, 512, 0, stream>>>(Ghi, Glo, Xhi, Xlo, Hp);
    k_score_rank<<<N, 256, 0, stream>>>(Hp, Mb, cols, cnt, coff, csr, as2, ad2, b2, out);
}

// Round 13
// 222.497 us; speedup vs baseline: 1.3489x; 1.0211x over previous
//
#include <hip/hip_runtime.h>
#include <math.h>

#define N 1536
#define E 24576
#define HD 128
#define D 1280
#define NW 24    // 1536/64 bitmask words per row
#define RT 16    // rows per block in k_h
#define LDK 40   // padded LDS row length (bf16 elems)
#define KSP 4    // split-K factor in k_h2mm
#define KSL 320  // K-slice length = D/KSP

typedef unsigned long long u64;
typedef unsigned short u16;
typedef unsigned int u32;
typedef __attribute__((ext_vector_type(8))) short bf16x8;
typedef __attribute__((ext_vector_type(4))) float f32x4;

__device__ __forceinline__ double lrelu(double v){ return v > 0.0 ? v : 0.2*v; }

// Branch-free f64 exp(x), rel err ~6e-15.
__device__ __forceinline__ double fexp(double x){
    double n = __builtin_rint(x * 1.4426950408889634);
    double r = __builtin_fma(-n, 0.6931471805599453, x);
    r = __builtin_fma(-n, 2.3190468138462996e-17, r);
    double p = 2.505210838544172e-8;
    p = __builtin_fma(p, r, 2.755731922398589e-7);
    p = __builtin_fma(p, r, 2.7557319223985893e-6);
    p = __builtin_fma(p, r, 2.48015873015873e-5);
    p = __builtin_fma(p, r, 1.984126984126984e-4);
    p = __builtin_fma(p, r, 1.3888888888888889e-3);
    p = __builtin_fma(p, r, 8.333333333333333e-3);
    p = __builtin_fma(p, r, 4.1666666666666664e-2);
    p = __builtin_fma(p, r, 1.6666666666666666e-1);
    p = __builtin_fma(p, r, 0.5);
    p = __builtin_fma(p, r, 1.0);
    p = __builtin_fma(p, r, 1.0);
    long long ni = (long long)n;
    double s = __longlong_as_double((u64)(ni + 1023) << 52);
    return (x < -700.0) ? 0.0 : p * s;
}

// Branch-free f32 exp(x), rel err ~2e-7, valid |x| <= 80.
__device__ __forceinline__ float fexpf_(float x){
    float n = __builtin_rintf(x * 1.44269504f);
    float r = __builtin_fmaf(-n, 0.693359375f, x);
    r = __builtin_fmaf(-n, -2.12194440e-4f, r);
    float p = 1.9841270e-4f;
    p = __builtin_fmaf(p, r, 1.3888889e-3f);
    p = __builtin_fmaf(p, r, 8.3333333e-3f);
    p = __builtin_fmaf(p, r, 4.1666667e-2f);
    p = __builtin_fmaf(p, r, 1.6666667e-1f);
    p = __builtin_fmaf(p, r, 0.5f);
    p = __builtin_fmaf(p, r, 1.0f);
    p = __builtin_fmaf(p, r, 1.0f);
    int ni = (int)n;
    float s = __uint_as_float((u32)(ni + 127) << 23);
    return p * s;
}

// f32 -> bf16(hi) + bf16(residual), both RNE
__device__ __forceinline__ void bsplit(float f, u16& h, u16& l){
    unsigned u = __float_as_uint(f);
    unsigned hr = (u + 0x7fffu + ((u>>16)&1u)) >> 16;
    h = (u16)hr;
    float hf = __uint_as_float(hr << 16);
    float r = f - hf;
    unsigned u2 = __float_as_uint(r);
    l = (u16)((u2 + 0x7fffu + ((u2>>16)&1u)) >> 16);
}

// ---- IN bitmask + in-degree incl. self-loop
__global__ void k_deg_in(const int* __restrict__ ei, u64* __restrict__ IN, int* __restrict__ deg){
    int idx = blockIdx.x*blockDim.x + threadIdx.x;
    if (idx < E){
        int s = ei[idx], t = ei[E+idx];
        atomicOr(&IN[(size_t)t*NW + (s>>6)], 1ULL << (s&63));
        atomicAdd(&deg[t], 1);
    } else if (idx < E+N){
        atomicAdd(&deg[idx-E], 1);
    }
}

// ---- exclusive scan of deg -> coff[0..N], cursor copy
__global__ void k_scan(const int* __restrict__ deg, int* __restrict__ coff, int* __restrict__ cursor){
    __shared__ int ls[256];
    int tid = threadIdx.x;
    int v[6]; int s = 0;
    for (int u=0; u<6; u++){ v[u] = s; s += deg[tid*6+u]; }
    ls[tid] = s; __syncthreads();
    for (int d=1; d<256; d<<=1){
        int t2 = (tid>=d) ? ls[tid-d] : 0;
        __syncthreads();
        ls[tid] += t2;
        __syncthreads();
    }
    int base = (tid>0) ? ls[tid-1] : 0;
    for (int u=0; u<6; u++){
        int o = base + v[u];
        coff[tid*6+u] = o; cursor[tid*6+u] = o;
    }
    if (tid==255) coff[N] = ls[255];
}

// ---- fill CSR of in-edge sources (u16 node ids)
__global__ void k_fill(const int* __restrict__ ei, int* __restrict__ cursor, u16* __restrict__ csr_src){
    int idx = blockIdx.x*blockDim.x + threadIdx.x;
    if (idx < E){
        int s = ei[idx], t = ei[E+idx];
        int p = atomicAdd(&cursor[t], 1);
        csr_src[p] = (u16)s;
    } else if (idx < E+N){
        int t = idx - E;
        int p = atomicAdd(&cursor[t], 1);
        csr_src[p] = (u16)t;
    }
}

// ---- 2-hop reachability (R9-proven): 64 threads, 1-hop list in LDS, 4 OR chains.
__global__ void k_mrow(const u64* __restrict__ IN, u64* __restrict__ Mb,
                       u16* __restrict__ cols, int* __restrict__ cnt){
    int i = blockIdx.x, ln = threadIdx.x;   // blockDim = 64
    __shared__ u64 m1[NW];
    __shared__ int scn[64];
    __shared__ u16 lst[N];
    u64 b = 0;
    if (ln < NW){
        b = IN[(size_t)i*NW + ln];
        if ((i>>6) == ln) b |= 1ULL << (i&63);
        m1[ln] = b;
    }
    int pc = (ln < NW) ? __popcll(b) : 0;
    scn[ln] = pc; __syncthreads();
    for (int d=1; d<64; d<<=1){
        int v = (ln>=d) ? scn[ln-d] : 0;
        __syncthreads();
        scn[ln] += v;
        __syncthreads();
    }
    {
        int idx = scn[ln] - pc;
        u64 bb = b;
        while (bb){
            int k = __ffsll((unsigned long long)bb) - 1;
            bb &= bb - 1;
            lst[idx++] = (u16)(ln*64 + k);
        }
    }
    __syncthreads();
    int nn = scn[63];
    u64 R0 = b, R1 = 0, R2 = 0, R3 = 0;
    int u = 0;
    if (ln < NW){
        for (; u+3 < nn; u += 4){
            R0 |= IN[(size_t)lst[u  ]*NW + ln];
            R1 |= IN[(size_t)lst[u+1]*NW + ln];
            R2 |= IN[(size_t)lst[u+2]*NW + ln];
            R3 |= IN[(size_t)lst[u+3]*NW + ln];
        }
        for (; u < nn; u++) R0 |= IN[(size_t)lst[u]*NW + ln];
    }
    u64 R = (R0 | R1) | (R2 | R3);
    if (ln < NW) Mb[(size_t)i*NW + ln] = R;
    __syncthreads();
    pc = (ln < NW) ? __popcll(R) : 0;
    scn[ln] = pc; __syncthreads();
    for (int d=1; d<64; d<<=1){
        int v = (ln>=d) ? scn[ln-d] : 0;
        __syncthreads();
        scn[ln] += v;
        __syncthreads();
    }
    if (ln == 63) cnt[i] = scn[63];
    int idx = scn[ln] - pc;
    u64 bb = R;
    while (bb){
        int k = __ffsll((unsigned long long)bb) - 1;
        bb &= bb - 1;
        cols[(size_t)i*N + idx++] = (u16)(ln*64 + k);
    }
}

// ---- h = x @ W1, all-f32. grid (D/256, N/RT).
__global__ void k_h(const float* __restrict__ x, const float* __restrict__ W1, float* __restrict__ h32){
    int rb = blockIdx.y*RT, tid = threadIdx.x;
    int col = blockIdx.x*256 + tid;
    __shared__ float xL[RT*HD];   // 8 KB
    for (int u=tid; u<RT*HD; u+=256) xL[u] = x[(size_t)rb*HD + u];
    __syncthreads();
    float acc[RT];
    #pragma unroll
    for (int r=0; r<RT; r++) acc[r] = 0.0f;
    const float* wp = &W1[col];
    #pragma unroll 4
    for (int k=0; k<HD; k++){
        float w = wp[(size_t)k*D];
        #pragma unroll
        for (int r=0; r<RT; r++) acc[r] = __builtin_fmaf(w, xL[r*HD + k], acc[r]);
    }
    #pragma unroll
    for (int r=0; r<RT; r++) h32[(size_t)(rb+r)*D + col] = acc[r];
}

// ---- hs1 = h@a_src1, hd1 = h@a_dst1 (f64 accum over f32 h)
__global__ void k_hv(const float* __restrict__ h32, const float* __restrict__ as1,
                     const float* __restrict__ ad1, double* __restrict__ hs1, double* __restrict__ hd1){
    int i = blockIdx.x, tid = threadIdx.x;
    __shared__ double ra[256], rb[256];
    double a = 0, b = 0;
    for (int d=tid; d<D; d+=256){
        double hv = (double)h32[(size_t)i*D + d];
        a += hv * (double)as1[d];
        b += hv * (double)ad1[d];
    }
    ra[tid] = a; rb[tid] = b; __syncthreads();
    for (int s=128; s>0; s>>=1){
        if (tid < s){ ra[tid] += ra[tid+s]; rb[tid] += rb[tid+s]; }
        __syncthreads();
    }
    if (tid == 0){ hs1[i] = ra[0]; hd1[i] = rb[0]; }
}

// ---- split xo into bf16 hi/lo planes
__global__ void k_split_x(const float* __restrict__ xo, u16* __restrict__ Xhi, u16* __restrict__ Xlo){
    int idx = (blockIdx.x*256 + threadIdx.x)*4;
    float4 v = *(const float4*)&xo[idx];
    ushort4 h, l;
    bsplit(v.x, h.x, l.x); bsplit(v.y, h.y, l.y);
    bsplit(v.z, h.z, l.z); bsplit(v.w, h.w, l.w);
    *(ushort4*)&Xhi[idx] = h;
    *(ushort4*)&Xlo[idx] = l;
}

// ---- stage-1 GAT: single-pass softmax, f32 gather, bf16 hi/lo epilogue
__global__ void k_gat(const int* __restrict__ coff, const u16* __restrict__ csr_src,
                      const double* __restrict__ hs1, const double* __restrict__ hd1,
                      const float* __restrict__ h32,
                      const float* __restrict__ b1, const float* __restrict__ w2,
                      u16* __restrict__ Ghi, u16* __restrict__ Glo){
    int t = blockIdx.x, tid = threadIdx.x;
    int o0 = coff[t], o1 = coff[t+1], dg = o1 - o0;
    __shared__ double red[256];
    __shared__ float als[256];
    __shared__ int ssrc[256];
    __shared__ double DD;
    double hdt = hd1[t];
    double dsum = 0.0;
    for (int j=tid; j<dg; j+=256){
        int s = csr_src[o0+j];
        double e = lrelu(hs1[s] + hdt);
        dsum += fexp(e);
    }
    red[tid] = dsum; __syncthreads();
    for (int step=128; step>0; step>>=1){
        if (tid < step) red[tid] += red[tid+step];
        __syncthreads();
    }
    if (tid == 0) DD = red[0];
    __syncthreads();
    double Dv = DD;
    float acc[5] = {0,0,0,0,0};
    for (int base=0; base<dg; base+=256){
        int j = base + tid;
        if (j < dg){
            int s = csr_src[o0+j];
            double e = lrelu(hs1[s] + hdt);
            als[tid] = (float)(fexp(e)/Dv); ssrc[tid] = s;
        }
        __syncthreads();
        int lim = min(256, dg-base);
        for (int u=0; u<lim; u+=2){
            float a0 = als[u];
            int s0 = ssrc[u];
            bool h1 = (u+1 < lim);
            float a1 = h1 ? als[u+1] : 0.0f;
            int s1 = h1 ? ssrc[u+1] : s0;
            const float* hp0 = &h32[(size_t)s0*D];
            const float* hp1 = &h32[(size_t)s1*D];
            #pragma unroll
            for (int q=0; q<5; q++)
                acc[q] = __builtin_fmaf(a1, hp1[tid + 256*q],
                         __builtin_fmaf(a0, hp0[tid + 256*q], acc[q]));
        }
        __syncthreads();
    }
    #pragma unroll
    for (int q=0; q<5; q++){
        int d = tid + 256*q;
        float g = (acc[q] + b1[d]) * w2[d];
        u16 gh, gl;
        bsplit(g, gh, gl);
        Ghi[(size_t)t*D + d] = gh;
        Glo[(size_t)t*D + d] = gl;
    }
}

// ---- dense H2 = G @ Xo^T via split-bf16 MFMA, v3:
// split-K x4 (576 blocks -> true 2 blocks/CU; one block's barrier drain overlaps
// the other's MFMA), 512 threads / 8 waves, wave tile 64x32, partials Hp[4].
__global__ __launch_bounds__(512, 4)
void k_h2mm(const u16* __restrict__ Ghi, const u16* __restrict__ Glo,
            const u16* __restrict__ Xhi, const u16* __restrict__ Xlo,
            float* __restrict__ Hp){
    __shared__ u16 As_hi[128*LDK], As_lo[128*LDK], Bs_hi[128*LDK], Bs_lo[128*LDK]; // 40 KB
    int tid = threadIdx.x;
    int ks = blockIdx.x & (KSP-1);
    int tile = blockIdx.x >> 2;
    int bm = tile / 12, bn = tile % 12;
    int r0 = tid >> 2;            // 0..127
    int kc = (tid & 3) * 8;       // 0,8,16,24
    int k0 = ks * KSL;
    size_t baseA = (size_t)(bm*128 + r0)*D + k0 + kc;
    size_t baseB = (size_t)(bn*128 + r0)*D + k0 + kc;
    int w = tid >> 6, L = tid & 63;
    int l16 = L & 15, qd = L >> 4;
    int wm = (w & 1)*64, wn = (w >> 1)*32;
    f32x4 acc[4][2];
    #pragma unroll
    for (int a=0; a<4; a++)
        #pragma unroll
        for (int b=0; b<2; b++) acc[a][b] = (f32x4){0.f,0.f,0.f,0.f};

    for (int kb = 0; kb < KSL; kb += 32){
        uint4 ah = *(const uint4*)&Ghi[baseA + kb];
        uint4 al = *(const uint4*)&Glo[baseA + kb];
        uint4 bh = *(const uint4*)&Xhi[baseB + kb];
        uint4 bl = *(const uint4*)&Xlo[baseB + kb];
        __syncthreads();   // previous compute done
        *(uint4*)&As_hi[r0*LDK + kc] = ah;
        *(uint4*)&As_lo[r0*LDK + kc] = al;
        *(uint4*)&Bs_hi[r0*LDK + kc] = bh;
        *(uint4*)&Bs_lo[r0*LDK + kc] = bl;
        __syncthreads();   // tiles ready
        bf16x8 ahi[4], alo[4];
        #pragma unroll
        for (int tm=0; tm<4; tm++){
            ahi[tm] = *(const bf16x8*)&As_hi[(wm + tm*16 + l16)*LDK + qd*8];
            alo[tm] = *(const bf16x8*)&As_lo[(wm + tm*16 + l16)*LDK + qd*8];
        }
        #pragma unroll
        for (int tn=0; tn<2; tn++){
            bf16x8 bhf = *(const bf16x8*)&Bs_hi[(wn + tn*16 + l16)*LDK + qd*8];
            bf16x8 blf = *(const bf16x8*)&Bs_lo[(wn + tn*16 + l16)*LDK + qd*8];
            #pragma unroll
            for (int tm=0; tm<4; tm++){
                acc[tm][tn] = __builtin_amdgcn_mfma_f32_16x16x32_bf16(ahi[tm], bhf, acc[tm][tn], 0, 0, 0);
                acc[tm][tn] = __builtin_amdgcn_mfma_f32_16x16x32_bf16(alo[tm], bhf, acc[tm][tn], 0, 0, 0);
                acc[tm][tn] = __builtin_amdgcn_mfma_f32_16x16x32_bf16(ahi[tm], blf, acc[tm][tn], 0, 0, 0);
            }
        }
    }
    // epilogue: C/D layout col=lane&15, row=quad*4+reg
    float* HO = Hp + (size_t)ks*N*N;
    #pragma unroll
    for (int tm=0; tm<4; tm++){
        int rbase = bm*128 + wm + tm*16 + qd*4;
        #pragma unroll
        for (int tn=0; tn<2; tn++){
            int cg = bn*128 + wn + tn*16 + l16;
            #pragma unroll
            for (int reg=0; reg<4; reg++)
                HO[(size_t)(rbase+reg)*N + cg] = acc[tm][tn][reg];
        }
    }
}

// ---- fused stage-2 score + rank: LDS-staged outputs, 8-way unrolled u16 edge walk.
// HL row = deterministic sum of the four split-K partials.
__global__ void k_score_rank(const float* __restrict__ Hp, const u64* __restrict__ Mb,
                             const u16* __restrict__ cols, const int* __restrict__ cnt,
                             const int* __restrict__ coff, const u16* __restrict__ csr_src,
                             const float* __restrict__ pas2, const float* __restrict__ pad2,
                             const float* __restrict__ pb2, float* __restrict__ out){
    int i = blockIdx.x, tid = threadIdx.x;
    __shared__ float HL[N];              // 6 KB
    __shared__ u64 MbL[NW];
    __shared__ u16 clL[N];               // 3 KB
    __shared__ u64 KL[N];                // 12 KB
    __shared__ float sigS[N];            // 6 KB
    __shared__ unsigned char keepB[N];   // 1.5 KB
    float* keepO = out + (size_t)N*N;
    for (int c=tid; c<N; c+=256){ sigS[c] = 0.0f; keepB[c] = 0; }
    for (int d=tid; d<N; d+=256){
        size_t o = (size_t)i*N + d;
        HL[d] = (Hp[o] + Hp[(size_t)N*N + o]) + (Hp[(size_t)2*N*N + o] + Hp[(size_t)3*N*N + o]);
    }
    if (tid < NW) MbL[tid] = Mb[(size_t)i*NW + tid];
    __syncthreads();
    float as2 = pas2[0], ad2 = pad2[0];
    double b2 = (double)pb2[0];
    int c0 = cnt[i];
    for (int c=tid; c<c0; c+=256){
        int t = cols[(size_t)i*N + c];
        float ht = HL[t];
        float zd = ad2 * ht;
        int o0 = coff[t], o1 = coff[t+1];
        double den = 0.0, nu = 0.0;
        int p = o0;
        for (; p+7 < o1; p += 8){
            int s[8]; float h[8]; float wv[8];
            #pragma unroll
            for (int q=0; q<8; q++) s[q] = csr_src[p+q];
            #pragma unroll
            for (int q=0; q<8; q++) h[q] = HL[s[q]];
            #pragma unroll
            for (int q=0; q<8; q++){
                bool v = (MbL[s[q]>>6] >> (s[q]&63)) & 1ULL;
                float z = __builtin_fmaf(as2, h[q], zd);
                float e = z > 0.f ? z : 0.2f*z;
                e = fminf(fmaxf(e, -80.f), 80.f);
                wv[q] = v ? fexpf_(e) : 0.0f;
            }
            #pragma unroll
            for (int q=0; q<8; q++){
                den += (double)wv[q];
                nu  += (double)(wv[q]*h[q]);
            }
        }
        for (; p < o1; p++){
            int s = csr_src[p];
            bool v = (MbL[s>>6] >> (s&63)) & 1ULL;
            float hs = HL[s];
            float z = __builtin_fmaf(as2, hs, zd);
            float e = z > 0.0f ? z : 0.2f*z;
            e = fminf(fmaxf(e, -80.0f), 80.0f);
            float w = v ? fexpf_(e) : 0.0f;
            den += (double)w;
            nu  += (double)(w * hs);
        }
        float sf = (float)(nu / fmax(den, 1e-12) + b2);
        clL[c] = (u16)t;
        u32 kb = __float_as_uint(sf);
        kb = (kb & 0x80000000u) ? ~kb : (kb | 0x80000000u);   // order-preserving map
        KL[c] = ((u64)kb << 16) | (u32)(1535 - t);            // tie-break: smaller col wins
    }
    __syncthreads();
    int k = (c0 + 1) >> 1;                 // ceil(0.5*size)
    for (int p=tid; p<c0; p+=256){
        u64 Kp = KL[p];
        int r = 0;
        for (int q=0; q<c0; q++) r += (int)(KL[q] > Kp);
        if (r < k){
            u32 kb = (u32)(Kp >> 16);
            u32 orig = (kb & 0x80000000u) ? (kb & 0x7fffffffu) : ~kb;
            float sf = __uint_as_float(orig);
            int col = clL[p];
            sigS[col] = 1.0f/(1.0f + fexpf_(fminf(fmaxf(-sf,-80.f),80.f)));
            keepB[col] = 1;
        }
    }
    __syncthreads();
    for (int c=tid; c<N; c+=256){
        out[(size_t)i*N + c]   = sigS[c];
        keepO[(size_t)i*N + c] = keepB[c] ? 1.0f : 0.0f;
    }
}

extern "C" void kernel_launch(void* const* d_in, const int* in_sizes, int n_in,
                              void* d_out, int out_size, void* d_ws, size_t ws_size,
                              hipStream_t stream){
    const float* x   = (const float*)d_in[0];
    const float* xo  = (const float*)d_in[1];
    const int*   ei  = (const int*)  d_in[2];
    // d_in[3] = batch (unused)
    const float* W1  = (const float*)d_in[4];
    const float* as1 = (const float*)d_in[5];
    const float* ad1 = (const float*)d_in[6];
    const float* b1  = (const float*)d_in[7];
    const float* w2  = (const float*)d_in[8];
    const float* as2 = (const float*)d_in[9];
    const float* ad2 = (const float*)d_in[10];
    const float* b2  = (const float*)d_in[11];
    float* out = (float*)d_out;

    char* w = (char*)d_ws;
    size_t o = 0;
    auto alloc = [&](size_t b)->char*{ char* r = w + o; o = (o + b + 255) & ~(size_t)255; return r; };

    float*  h32   = (float*) alloc((size_t)N*D*4);
    float*  Hp    = (float*) alloc((size_t)KSP*N*N*4);  // 4 split-K partials (37.7 MB)
    u16*    Ghi   = (u16*)   alloc((size_t)N*D*2);
    u16*    Glo   = (u16*)   alloc((size_t)N*D*2);
    u16*    Xhi   = (u16*)   alloc((size_t)N*D*2);
    u16*    Xlo   = (u16*)   alloc((size_t)N*D*2);
    u64*    IN    = (u64*)   alloc((size_t)N*NW*8);   // 294912 B, 256-aligned
    int*    deg   = (int*)   alloc((size_t)N*4);      // contiguous after IN -> one memset
    u64*    Mb    = (u64*)   alloc((size_t)N*NW*8);
    double* hs1   = (double*)alloc((size_t)N*8);
    double* hd1   = (double*)alloc((size_t)N*8);
    int*    coff  = (int*)   alloc((size_t)(N+1)*4);
    int*    cursor= (int*)   alloc((size_t)N*4);
    u16*    csr   = (u16*)   alloc((size_t)(E+N)*2);
    u16*    cols  = (u16*)   alloc((size_t)N*N*2);
    int*    cnt   = (int*)   alloc((size_t)N*4);

    hipMemsetAsync(IN, 0, (size_t)N*NW*8 + (size_t)N*4, stream);  // IN + deg

    k_deg_in <<<(E+N+255)/256, 256, 0, stream>>>(ei, IN, deg);
    k_scan   <<<1, 256, 0, stream>>>(deg, coff, cursor);
    k_fill   <<<(E+N+255)/256, 256, 0, stream>>>(ei, cursor, csr);
    k_split_x<<<(N*D)/(256*4), 256, 0, stream>>>(xo, Xhi, Xlo);
    k_mrow   <<<N, 64, 0, stream>>>(IN, Mb, cols, cnt);
    k_h      <<<dim3(D/256, N/RT), 256, 0, stream>>>(x, W1, h32);
    k_hv     <<<N, 256, 0, stream>>>(h32, as1, ad1, hs1, hd1);
    k_gat    <<<N, 256, 0, stream>>>(coff, csr, hs1, hd1, h32, b1, w2, Ghi, Glo);
    k_h2mm   <<<144*KSP, 512, 0, stream>>>(Ghi, Glo, Xhi, Xlo, Hp);
    k_score_rank<<<N, 256, 0, stream>>>(Hp, Mb, cols, cnt, coff, csr, as2, ad2, b2, out);
}